// Round 1
// baseline (2732.213 us; speedup 1.0000x reference)
//
#include <hip/hip_runtime.h>
#include <math.h>

// ---------------------------------------------------------------------------
// VQ-VAE eval forward: conv stack -> 1x1 conv -> VQ (argmin codebook) ->
// classifier head. All fp32 (CDNA4 has no fp32 MFMA; vector ALU).
// Workspace layout (float offsets), aggressive buffer reuse, ~155 MB:
//   p1  [32,16,112,112]  @ 0          (6,422,528)
//   p2  [32,32,56,56]    @ 6,422,528  (3,211,264)
//   h3  [32,64,56,56]    @ 0          (reuses p1, dead)
//   h4  [32,128,56,56]   @ 9,633,792  (12,845,056)
//   hq  [32,128,56,56]   @ 22,478,848 (12,845,056)
//   qn  [32,128,56,56]   @ 0          (reuses h3/p2/h4-prefix, all dead)
//   ind [100352] int     @ 35,323,904
//   enorm [1024]         @ 35,424,256
//   part [784*4096]      @ 35,425,536
//   z    [4096]          @ 38,636,800
//   bsum [50176]         @ 38,640,896   -> end 38,691,072 floats (~154.8 MB)
// ---------------------------------------------------------------------------

#define OFF_P1    0u
#define OFF_P2    6422528u
#define OFF_H3    0u
#define OFF_H4    9633792u
#define OFF_HQ    22478848u
#define OFF_QN    0u
#define OFF_IND   35323904u
#define OFF_EN    35424256u
#define OFF_PART  35425536u
#define OFF_Z     38636800u
#define OFF_BSUM  38640896u

#define BN_EPS 1e-5f

// ---------------- embed norms: enorm[c] = sum_d embed[d][c]^2 ----------------
__global__ __launch_bounds__(256) void k_enorm(const float* __restrict__ embed,
                                               float* __restrict__ enorm) {
  int c = blockIdx.x * 256 + threadIdx.x;
  if (c < 1024) {
    float s = 0.f;
    for (int d = 0; d < 128; ++d) { float e = embed[d * 1024 + c]; s += e * e; }
    enorm[c] = s;
  }
}

// ------------- conv1 (1->16, 3x3 SAME) + BN + ReLU + 2x2 maxpool -------------
// one thread = one pooled output (b, c, yo, xo); reads 4x4 input window.
__global__ __launch_bounds__(256) void k_conv1_pool(
    const float* __restrict__ x, const float* __restrict__ w,
    const float* __restrict__ cb, const float* __restrict__ g,
    const float* __restrict__ bb, const float* __restrict__ m,
    const float* __restrict__ v, float* __restrict__ p1) {
  int gid = blockIdx.x * 256 + threadIdx.x;
  if (gid >= 32 * 16 * 112 * 112) return;
  int xo = gid % 112; int t = gid / 112;
  int yo = t % 112;  t /= 112;
  int c = t % 16;    int b = t / 16;

  float wreg[9];
#pragma unroll
  for (int i = 0; i < 9; ++i) wreg[i] = w[c * 9 + i];
  float inv  = g[c] * rsqrtf(v[c] + BN_EPS);
  float sh   = bb[c] - m[c] * inv;
  float bias = cb[c];

  const float* xb = x + b * 224 * 224;
  int r0 = 2 * yo - 1, c0 = 2 * xo - 1;
  float win[4][4];
#pragma unroll
  for (int r = 0; r < 4; ++r) {
    int row = r0 + r;
    bool rv = (row >= 0) && (row < 224);
#pragma unroll
    for (int cc = 0; cc < 4; ++cc) {
      int col = c0 + cc;
      win[r][cc] = (rv && col >= 0 && col < 224) ? xb[row * 224 + col] : 0.f;
    }
  }
  float mx = -3.4e38f;
#pragma unroll
  for (int dy = 0; dy < 2; ++dy)
#pragma unroll
    for (int dx = 0; dx < 2; ++dx) {
      float a = bias;
#pragma unroll
      for (int ky = 0; ky < 3; ++ky)
#pragma unroll
        for (int kx = 0; kx < 3; ++kx)
          a += win[dy + ky][dx + kx] * wreg[ky * 3 + kx];
      a = a * inv + sh;
      a = fmaxf(a, 0.f);
      mx = fmaxf(mx, a);
    }
  p1[gid] = mx;  // gid ordering == [b][c][yo][xo] flat
}

// ------------- conv2 (16->32) + BN + ReLU + pool; 4 co per thread -------------
__global__ __launch_bounds__(256) void k_conv2_pool(
    const float* __restrict__ p1, const float* __restrict__ w,
    const float* __restrict__ cb, const float* __restrict__ g,
    const float* __restrict__ bb, const float* __restrict__ m,
    const float* __restrict__ v, float* __restrict__ p2) {
  int gid = blockIdx.x * 256 + threadIdx.x;
  if (gid >= 32 * 8 * 56 * 56) return;
  int xo = gid % 56; int t = gid / 56;
  int yo = t % 56;  t /= 56;
  int cog = t % 8;  int b = t / 8;

  float acc[4][4];  // [coi][dy*2+dx]
#pragma unroll
  for (int i = 0; i < 4; ++i)
#pragma unroll
    for (int j = 0; j < 4; ++j) acc[i][j] = 0.f;

  const float* in = p1 + b * 16 * 112 * 112;
  int r0 = 2 * yo - 1, c0 = 2 * xo - 1;
  for (int ci = 0; ci < 16; ++ci) {
    const float* ip = in + ci * 112 * 112;
    float win[4][4];
#pragma unroll
    for (int r = 0; r < 4; ++r) {
      int row = r0 + r;
      bool rv = (row >= 0) && (row < 112);
#pragma unroll
      for (int cc = 0; cc < 4; ++cc) {
        int col = c0 + cc;
        win[r][cc] = (rv && col >= 0 && col < 112) ? ip[row * 112 + col] : 0.f;
      }
    }
#pragma unroll
    for (int coi = 0; coi < 4; ++coi) {
      const float* wp = w + ((cog * 4 + coi) * 16 + ci) * 9;
      float w00 = wp[0], w01 = wp[1], w02 = wp[2];
      float w10 = wp[3], w11 = wp[4], w12 = wp[5];
      float w20 = wp[6], w21 = wp[7], w22 = wp[8];
#pragma unroll
      for (int dy = 0; dy < 2; ++dy)
#pragma unroll
        for (int dx = 0; dx < 2; ++dx)
          acc[coi][dy * 2 + dx] +=
              win[dy + 0][dx + 0] * w00 + win[dy + 0][dx + 1] * w01 + win[dy + 0][dx + 2] * w02 +
              win[dy + 1][dx + 0] * w10 + win[dy + 1][dx + 1] * w11 + win[dy + 1][dx + 2] * w12 +
              win[dy + 2][dx + 0] * w20 + win[dy + 2][dx + 1] * w21 + win[dy + 2][dx + 2] * w22;
    }
  }
#pragma unroll
  for (int coi = 0; coi < 4; ++coi) {
    int co = cog * 4 + coi;
    float inv  = g[co] * rsqrtf(v[co] + BN_EPS);
    float sh   = bb[co] - m[co] * inv;
    float bias = cb[co];
    float mx = -3.4e38f;
#pragma unroll
    for (int pt = 0; pt < 4; ++pt) {
      float a = (acc[coi][pt] + bias) * inv + sh;
      a = fmaxf(a, 0.f);
      mx = fmaxf(mx, a);
    }
    p2[((b * 32 + co) * 56 + yo) * 56 + xo] = mx;
  }
}

// ----- generic 3x3 SAME conv on 56x56 + BN + ReLU; 4 x-cols x 4 co /thread ----
template <int CI, int CO>
__global__ __launch_bounds__(256) void k_conv3x3(
    const float* __restrict__ in_, const float* __restrict__ w,
    const float* __restrict__ cb, const float* __restrict__ g,
    const float* __restrict__ bb, const float* __restrict__ m,
    const float* __restrict__ v, float* __restrict__ out_) {
  int gid = blockIdx.x * 256 + threadIdx.x;
  if (gid >= 32 * (CO / 4) * 56 * 14) return;
  int xq = gid % 14; int t = gid / 14;
  int y = t % 56;   t /= 56;
  int cog = t % (CO / 4); int b = t / (CO / 4);
  int x0 = xq * 4;

  float acc[4][4];  // [coi][xi]
#pragma unroll
  for (int i = 0; i < 4; ++i)
#pragma unroll
    for (int j = 0; j < 4; ++j) acc[i][j] = 0.f;

  const float* inb = in_ + b * CI * 3136;
  for (int ci = 0; ci < CI; ++ci) {
    const float* ip = inb + ci * 3136;
#pragma unroll
    for (int ky = 0; ky < 3; ++ky) {
      int row = y + ky - 1;
      float r_[6];
      if (row >= 0 && row < 56) {
        const float* rp = ip + row * 56;
#pragma unroll
        for (int i = 0; i < 6; ++i) {
          int col = x0 - 1 + i;
          r_[i] = (col >= 0 && col < 56) ? rp[col] : 0.f;
        }
      } else {
#pragma unroll
        for (int i = 0; i < 6; ++i) r_[i] = 0.f;
      }
#pragma unroll
      for (int coi = 0; coi < 4; ++coi) {
        const float* wp = w + (((cog * 4 + coi) * CI + ci) * 3 + ky) * 3;
        float w0 = wp[0], w1 = wp[1], w2 = wp[2];
#pragma unroll
        for (int xi = 0; xi < 4; ++xi)
          acc[coi][xi] += r_[xi] * w0 + r_[xi + 1] * w1 + r_[xi + 2] * w2;
      }
    }
  }
#pragma unroll
  for (int coi = 0; coi < 4; ++coi) {
    int co = cog * 4 + coi;
    float inv  = g[co] * rsqrtf(v[co] + BN_EPS);
    float sh   = bb[co] - m[co] * inv;
    float bias = cb[co];
    float* op = out_ + ((b * CO + co) * 56 + y) * 56 + x0;
#pragma unroll
    for (int xi = 0; xi < 4; ++xi) {
      float a = (acc[coi][xi] + bias) * inv + sh;
      op[xi] = fmaxf(a, 0.f);
    }
  }
}

// --------------------- qconv: 1x1 conv 128->128 + bias -----------------------
// block = (b, 64-pixel tile); stage input tile [128ci][64p] in LDS.
__global__ __launch_bounds__(256) void k_qconv(const float* __restrict__ h4,
                                               const float* __restrict__ wq,
                                               const float* __restrict__ qb,
                                               float* __restrict__ hq) {
  int bi = blockIdx.x / 49;
  int p0 = (blockIdx.x % 49) * 64;
  __shared__ __align__(16) float hl[128][64];
  int tid = threadIdx.x;
  const float* in = h4 + (size_t)bi * 128 * 3136 + p0;
  for (int i = 0; i < 32; ++i) {
    int ci = i * 4 + tid / 64; int p = tid % 64;
    hl[ci][p] = in[ci * 3136 + p];
  }
  __syncthreads();
  int cog = tid / 16;  // 16 groups x 8 co
  int pg  = tid % 16;  // 16 groups x 4 p
  int co0 = cog * 8, pl = pg * 4;
  float acc[8][4];
#pragma unroll
  for (int i = 0; i < 8; ++i)
#pragma unroll
    for (int j = 0; j < 4; ++j) acc[i][j] = 0.f;
  for (int ci = 0; ci < 128; ++ci) {
    float4 hv = *(const float4*)&hl[ci][pl];
#pragma unroll
    for (int coi = 0; coi < 8; ++coi) {
      float wv = wq[(co0 + coi) * 128 + ci];
      acc[coi][0] += hv.x * wv; acc[coi][1] += hv.y * wv;
      acc[coi][2] += hv.z * wv; acc[coi][3] += hv.w * wv;
    }
  }
#pragma unroll
  for (int coi = 0; coi < 8; ++coi) {
    float bias = qb[co0 + coi];
    float* op = hq + ((size_t)bi * 128 + co0 + coi) * 3136 + p0 + pl;
#pragma unroll
    for (int xi = 0; xi < 4; ++xi) op[xi] = acc[coi][xi] + bias;
  }
}

// --------------- VQ: argmin_c ( enorm[c] - 2 * <flat_n, embed_c> ) -----------
// ||flat||^2 omitted (argmin-invariant). block = 64-point tile; codes chunked
// by 64 with embed chunk in LDS [d][c] (natural orientation, conflict-free).
// thread tile: 4 points x 4 codes; code id c = cg + 16*ci (strided for banks).
__global__ __launch_bounds__(256) void k_vq_argmin(const float* __restrict__ hq,
                                                   const float* __restrict__ embed,
                                                   const float* __restrict__ enorm,
                                                   int* __restrict__ ind) {
  int bi = blockIdx.x / 49;
  int p0 = (blockIdx.x % 49) * 64;
  __shared__ __align__(16) float fl[64][132];  // [p][d], pad 132
  __shared__ __align__(16) float el[128][64];  // [d][c]
  int tid = threadIdx.x;
  const float* in = hq + (size_t)bi * 128 * 3136 + p0;
  for (int i = 0; i < 32; ++i) {
    int d = i * 4 + tid / 64; int p = tid % 64;
    fl[p][d] = in[d * 3136 + p];
  }
  int cg = tid % 16;  // code group (lanes 0..15 consecutive)
  int pg = tid / 16;  // point group (4 points)
  float best[4]; int bidx[4];
#pragma unroll
  for (int i = 0; i < 4; ++i) { best[i] = 3.4e38f; bidx[i] = 0; }

  for (int cc = 0; cc < 16; ++cc) {
    __syncthreads();  // also covers fl on first iteration
    for (int i = 0; i < 32; ++i) {
      int d = i * 4 + tid / 64; int c = tid % 64;
      el[d][c] = embed[d * 1024 + cc * 64 + c];
    }
    __syncthreads();
    float acc[4][4];
#pragma unroll
    for (int i = 0; i < 4; ++i)
#pragma unroll
      for (int j = 0; j < 4; ++j) acc[i][j] = 0.f;

#pragma unroll 2
    for (int d = 0; d < 128; d += 4) {
      const float4 f0 = *(const float4*)&fl[pg * 4 + 0][d];
      const float4 f1 = *(const float4*)&fl[pg * 4 + 1][d];
      const float4 f2 = *(const float4*)&fl[pg * 4 + 2][d];
      const float4 f3 = *(const float4*)&fl[pg * 4 + 3][d];
#pragma unroll
      for (int ci = 0; ci < 4; ++ci) {
        const int c = cg + 16 * ci;
        const float e0 = el[d + 0][c];
        const float e1 = el[d + 1][c];
        const float e2 = el[d + 2][c];
        const float e3 = el[d + 3][c];
        acc[0][ci] += f0.x * e0 + f0.y * e1 + f0.z * e2 + f0.w * e3;
        acc[1][ci] += f1.x * e0 + f1.y * e1 + f1.z * e2 + f1.w * e3;
        acc[2][ci] += f2.x * e0 + f2.y * e1 + f2.z * e2 + f2.w * e3;
        acc[3][ci] += f3.x * e0 + f3.y * e1 + f3.z * e2 + f3.w * e3;
      }
    }
#pragma unroll
    for (int pi = 0; pi < 4; ++pi)
#pragma unroll
      for (int ci = 0; ci < 4; ++ci) {
        int c = cc * 64 + cg + 16 * ci;
        float dist = enorm[c] - 2.f * acc[pi][ci];
        // strict < keeps earliest index (per-thread candidates ascend in c)
        if (dist < best[pi]) { best[pi] = dist; bidx[pi] = c; }
      }
  }
  // reduce across the 16 cg lanes (consecutive); first-min tie-break
#pragma unroll
  for (int pi = 0; pi < 4; ++pi) {
    float b_ = best[pi]; int x_ = bidx[pi];
    for (int off = 8; off >= 1; off >>= 1) {
      float ob = __shfl_xor(b_, off);
      int   ox = __shfl_xor(x_, off);
      if (ob < b_ || (ob == b_ && ox < x_)) { b_ = ob; x_ = ox; }
    }
    if (cg == 0) ind[bi * 3136 + p0 + pg * 4 + pi] = x_;
  }
}

// ------ gather codes to NCHW (qn) + per-block sum of (q-h)^2 into bsum -------
__global__ __launch_bounds__(256) void k_gather_diff(const float* __restrict__ hq,
                                                     const float* __restrict__ embed,
                                                     const int* __restrict__ ind,
                                                     float* __restrict__ qn,
                                                     float* __restrict__ bsum) {
  int gid = blockIdx.x * 256 + threadIdx.x;  // over [b][d][p] flat
  int p = gid % 3136; int t = gid / 3136; int d = t % 128; int b = t / 128;
  int idx = ind[b * 3136 + p];
  float q = embed[d * 1024 + idx];
  float h = hq[gid];
  qn[gid] = q;
  float df = q - h;
  float val = df * df;
  for (int off = 32; off >= 1; off >>= 1) val += __shfl_down(val, off);
  __shared__ float red[4];
  int lane = threadIdx.x & 63, wv = threadIdx.x >> 6;
  if (lane == 0) red[wv] = val;
  __syncthreads();
  if (threadIdx.x == 0) bsum[blockIdx.x] = red[0] + red[1] + red[2] + red[3];
}

// ------------------- fc1 split-K partials: z_pre = qn @ w^T ------------------
// 784 blocks x K-span 512; LDS tiles ql[32][64], wl[128][64] (XOR-swizzled);
// thread tile 4b x 4j with strided ids (b = bg+8*bi, j = jg+32*ji) for banks.
__global__ __launch_bounds__(256) void k_fc1(const float* __restrict__ qn,
                                             const float* __restrict__ w,
                                             float* __restrict__ part) {
  int kb = blockIdx.x;
  int k0 = kb * 512;
  __shared__ __align__(16) float ql[32][64];
  __shared__ __align__(16) float wl[128][64];
  int tid = threadIdx.x;
  int bg = tid / 32, jg = tid % 32;
  float acc[4][4];
#pragma unroll
  for (int i = 0; i < 4; ++i)
#pragma unroll
    for (int j = 0; j < 4; ++j) acc[i][j] = 0.f;

  for (int kt = 0; kt < 512; kt += 64) {
    __syncthreads();
#pragma unroll
    for (int i = 0; i < 8; ++i) {
      int b = i * 4 + tid / 64; int k = tid % 64;
      ql[b][k ^ ((b & 15) << 2)] = qn[(size_t)b * 401408 + k0 + kt + k];
    }
#pragma unroll 4
    for (int i = 0; i < 32; ++i) {
      int j = i * 4 + tid / 64; int k = tid % 64;
      wl[j][k ^ ((j & 15) << 2)] = w[(size_t)j * 401408 + k0 + kt + k];
    }
    __syncthreads();
    for (int k = 0; k < 64; k += 4) {
      float4 qv[4], wv[4];
#pragma unroll
      for (int bi = 0; bi < 4; ++bi) {
        int b = bg + 8 * bi;
        qv[bi] = *(const float4*)&ql[b][k ^ ((b & 15) << 2)];
      }
#pragma unroll
      for (int ji = 0; ji < 4; ++ji) {
        int j = jg + 32 * ji;
        wv[ji] = *(const float4*)&wl[j][k ^ ((j & 15) << 2)];
      }
#pragma unroll
      for (int bi = 0; bi < 4; ++bi)
#pragma unroll
        for (int ji = 0; ji < 4; ++ji)
          acc[bi][ji] += qv[bi].x * wv[ji].x + qv[bi].y * wv[ji].y +
                         qv[bi].z * wv[ji].z + qv[bi].w * wv[ji].w;
    }
  }
#pragma unroll
  for (int bi = 0; bi < 4; ++bi)
#pragma unroll
    for (int ji = 0; ji < 4; ++ji)
      part[(size_t)kb * 4096 + (bg + 8 * bi) * 128 + (jg + 32 * ji)] = acc[bi][ji];
}

// --------------- reduce split-K partials, add bias, leaky_relu ---------------
__global__ __launch_bounds__(256) void k_fc1_reduce(const float* __restrict__ part,
                                                    const float* __restrict__ fb,
                                                    float* __restrict__ z) {
  int t = blockIdx.x * 256 + threadIdx.x;  // 4096 = 32b x 128j
  if (t >= 4096) return;
  float s = 0.f;
  for (int i = 0; i < 784; ++i) s += part[(size_t)i * 4096 + t];
  s += fb[t % 128];
  z[t] = (s > 0.f) ? s : 0.01f * s;
}

// ---------- head: fc2 + log_softmax + diff finalize (single block) -----------
__global__ __launch_bounds__(384) void k_head(const float* __restrict__ z,
                                              const float* __restrict__ w2,
                                              const float* __restrict__ b2,
                                              const float* __restrict__ bsum,
                                              float* __restrict__ out) {
  __shared__ float lg[32][11];
  __shared__ float lse[32];
  __shared__ float sred[384];
  int t = threadIdx.x;

  // diff partial-sum reduction (50176 block sums)
  float s = 0.f;
  for (int i = t; i < 50176; i += 384) s += bsum[i];
  sred[t] = s;
  __syncthreads();
  if (t < 128) sred[t] += sred[t + 128] + sred[t + 256];
  __syncthreads();
  for (int st = 64; st >= 1; st >>= 1) {
    if (t < st) sred[t] += sred[t + st];
    __syncthreads();
  }

  // logits
  if (t < 352) {
    int b = t / 11, j = t % 11;
    float acc = b2[j];
    for (int d = 0; d < 128; ++d) acc += z[b * 128 + d] * w2[j * 128 + d];
    lg[b][j] = acc;
  }
  __syncthreads();
  if (t < 32) {
    float mx = -3.4e38f;
    for (int j = 0; j < 11; ++j) mx = fmaxf(mx, lg[t][j]);
    float se = 0.f;
    for (int j = 0; j < 11; ++j) se += expf(lg[t][j] - mx);
    lse[t] = mx + logf(se);
  }
  __syncthreads();
  if (t < 352) { int b = t / 11, j = t % 11; out[t] = lg[b][j] - lse[b]; }
  if (t == 352) out[352] = 1.25f * sred[0] / 12845056.0f;
}

// ---------------------------------------------------------------------------
extern "C" void kernel_launch(void* const* d_in, const int* in_sizes, int n_in,
                              void* d_out, int out_size, void* d_ws, size_t ws_size,
                              hipStream_t stream) {
  const float* x    = (const float*)d_in[0];
  const float* c1w  = (const float*)d_in[1];
  const float* c1b  = (const float*)d_in[2];
  const float* c2w  = (const float*)d_in[3];
  const float* c2b  = (const float*)d_in[4];
  const float* c3w  = (const float*)d_in[5];
  const float* c3b  = (const float*)d_in[6];
  const float* c4w  = (const float*)d_in[7];
  const float* c4b  = (const float*)d_in[8];
  const float* bn1g = (const float*)d_in[9];
  const float* bn1b = (const float*)d_in[10];
  const float* bn1m = (const float*)d_in[11];
  const float* bn1v = (const float*)d_in[12];
  const float* bn2g = (const float*)d_in[13];
  const float* bn2b = (const float*)d_in[14];
  const float* bn2m = (const float*)d_in[15];
  const float* bn2v = (const float*)d_in[16];
  const float* bn3g = (const float*)d_in[17];
  const float* bn3b = (const float*)d_in[18];
  const float* bn3m = (const float*)d_in[19];
  const float* bn3v = (const float*)d_in[20];
  const float* bn4g = (const float*)d_in[21];
  const float* bn4b = (const float*)d_in[22];
  const float* bn4m = (const float*)d_in[23];
  const float* bn4v = (const float*)d_in[24];
  const float* qw   = (const float*)d_in[25];
  const float* qcb  = (const float*)d_in[26];
  const float* emb  = (const float*)d_in[27];
  const float* f1w  = (const float*)d_in[28];
  const float* f1b  = (const float*)d_in[29];
  const float* f2w  = (const float*)d_in[30];
  const float* f2b  = (const float*)d_in[31];

  float* ws  = (float*)d_ws;
  float* out = (float*)d_out;

  float* p1   = ws + OFF_P1;
  float* p2   = ws + OFF_P2;
  float* h3   = ws + OFF_H3;
  float* h4   = ws + OFF_H4;
  float* hq   = ws + OFF_HQ;
  float* qn   = ws + OFF_QN;
  int*   ind  = (int*)(ws + OFF_IND);
  float* en   = ws + OFF_EN;
  float* part = ws + OFF_PART;
  float* z    = ws + OFF_Z;
  float* bsum = ws + OFF_BSUM;

  k_enorm<<<4, 256, 0, stream>>>(emb, en);
  k_conv1_pool<<<25088, 256, 0, stream>>>(x, c1w, c1b, bn1g, bn1b, bn1m, bn1v, p1);
  k_conv2_pool<<<3136, 256, 0, stream>>>(p1, c2w, c2b, bn2g, bn2b, bn2m, bn2v, p2);
  k_conv3x3<32, 64><<<1568, 256, 0, stream>>>(p2, c3w, c3b, bn3g, bn3b, bn3m, bn3v, h3);
  k_conv3x3<64, 128><<<3136, 256, 0, stream>>>(h3, c4w, c4b, bn4g, bn4b, bn4m, bn4v, h4);
  k_qconv<<<1568, 256, 0, stream>>>(h4, qw, qcb, hq);
  k_vq_argmin<<<1568, 256, 0, stream>>>(hq, emb, en, ind);
  k_gather_diff<<<50176, 256, 0, stream>>>(hq, emb, ind, qn, bsum);
  k_fc1<<<784, 256, 0, stream>>>(qn, f1w, part);
  k_fc1_reduce<<<16, 256, 0, stream>>>(part, f1b, z);
  k_head<<<1, 384, 0, stream>>>(z, f2w, f2b, bsum, out);
}

// Round 4
// 1736.095 us; speedup vs baseline: 1.5738x; 1.5738x over previous
//
#include <hip/hip_runtime.h>
#include <math.h>

// ---------------------------------------------------------------------------
// VQ-VAE eval forward: conv stack -> 1x1 conv -> VQ (argmin codebook) ->
// classifier head. All fp32 (CDNA4 has no fp32 MFMA; vector ALU).
// R1: conv3/conv4 rewritten as LDS-staged tile kernels (baseline was
// latency-bound: VALUBusy 21%, 8% of VALU roofline).
// R2/R3: identical resubmits (benches never ran - broker timeouts).
// Workspace layout (float offsets), aggressive buffer reuse, ~155 MB:
//   p1  [32,16,112,112]  @ 0          (6,422,528)
//   p2  [32,32,56,56]    @ 6,422,528  (3,211,264)
//   h3  [32,64,56,56]    @ 0          (reuses p1, dead)
//   h4  [32,128,56,56]   @ 9,633,792  (12,845,056)
//   hq  [32,128,56,56]   @ 22,478,848 (12,845,056)
//   qn  [32,128,56,56]   @ 0          (reuses h3/p2/h4-prefix, all dead)
//   ind [100352] int     @ 35,323,904
//   enorm [1024]         @ 35,424,256
//   part [784*4096]      @ 35,425,536
//   z    [4096]          @ 38,636,800
//   bsum [50176]         @ 38,640,896   -> end 38,691,072 floats (~154.8 MB)
// ---------------------------------------------------------------------------

#define OFF_P1    0u
#define OFF_P2    6422528u
#define OFF_H3    0u
#define OFF_H4    9633792u
#define OFF_HQ    22478848u
#define OFF_QN    0u
#define OFF_IND   35323904u
#define OFF_EN    35424256u
#define OFF_PART  35425536u
#define OFF_Z     38636800u
#define OFF_BSUM  38640896u

#define BN_EPS 1e-5f

// ---------------- embed norms: enorm[c] = sum_d embed[d][c]^2 ----------------
__global__ __launch_bounds__(256) void k_enorm(const float* __restrict__ embed,
                                               float* __restrict__ enorm) {
  int c = blockIdx.x * 256 + threadIdx.x;
  if (c < 1024) {
    float s = 0.f;
    for (int d = 0; d < 128; ++d) { float e = embed[d * 1024 + c]; s += e * e; }
    enorm[c] = s;
  }
}

// ------------- conv1 (1->16, 3x3 SAME) + BN + ReLU + 2x2 maxpool -------------
// one thread = one pooled output (b, c, yo, xo); reads 4x4 input window.
__global__ __launch_bounds__(256) void k_conv1_pool(
    const float* __restrict__ x, const float* __restrict__ w,
    const float* __restrict__ cb, const float* __restrict__ g,
    const float* __restrict__ bb, const float* __restrict__ m,
    const float* __restrict__ v, float* __restrict__ p1) {
  int gid = blockIdx.x * 256 + threadIdx.x;
  if (gid >= 32 * 16 * 112 * 112) return;
  int xo = gid % 112; int t = gid / 112;
  int yo = t % 112;  t /= 112;
  int c = t % 16;    int b = t / 16;

  float wreg[9];
#pragma unroll
  for (int i = 0; i < 9; ++i) wreg[i] = w[c * 9 + i];
  float inv  = g[c] * rsqrtf(v[c] + BN_EPS);
  float sh   = bb[c] - m[c] * inv;
  float bias = cb[c];

  const float* xb = x + b * 224 * 224;
  int r0 = 2 * yo - 1, c0 = 2 * xo - 1;
  float win[4][4];
#pragma unroll
  for (int r = 0; r < 4; ++r) {
    int row = r0 + r;
    bool rv = (row >= 0) && (row < 224);
#pragma unroll
    for (int cc = 0; cc < 4; ++cc) {
      int col = c0 + cc;
      win[r][cc] = (rv && col >= 0 && col < 224) ? xb[row * 224 + col] : 0.f;
    }
  }
  float mx = -3.4e38f;
#pragma unroll
  for (int dy = 0; dy < 2; ++dy)
#pragma unroll
    for (int dx = 0; dx < 2; ++dx) {
      float a = bias;
#pragma unroll
      for (int ky = 0; ky < 3; ++ky)
#pragma unroll
        for (int kx = 0; kx < 3; ++kx)
          a += win[dy + ky][dx + kx] * wreg[ky * 3 + kx];
      a = a * inv + sh;
      a = fmaxf(a, 0.f);
      mx = fmaxf(mx, a);
    }
  p1[gid] = mx;  // gid ordering == [b][c][yo][xo] flat
}

// ------------- conv2 (16->32) + BN + ReLU + pool; 4 co per thread -------------
__global__ __launch_bounds__(256) void k_conv2_pool(
    const float* __restrict__ p1, const float* __restrict__ w,
    const float* __restrict__ cb, const float* __restrict__ g,
    const float* __restrict__ bb, const float* __restrict__ m,
    const float* __restrict__ v, float* __restrict__ p2) {
  int gid = blockIdx.x * 256 + threadIdx.x;
  if (gid >= 32 * 8 * 56 * 56) return;
  int xo = gid % 56; int t = gid / 56;
  int yo = t % 56;  t /= 56;
  int cog = t % 8;  int b = t / 8;

  float acc[4][4];  // [coi][dy*2+dx]
#pragma unroll
  for (int i = 0; i < 4; ++i)
#pragma unroll
    for (int j = 0; j < 4; ++j) acc[i][j] = 0.f;

  const float* in = p1 + b * 16 * 112 * 112;
  int r0 = 2 * yo - 1, c0 = 2 * xo - 1;
  for (int ci = 0; ci < 16; ++ci) {
    const float* ip = in + ci * 112 * 112;
    float win[4][4];
#pragma unroll
    for (int r = 0; r < 4; ++r) {
      int row = r0 + r;
      bool rv = (row >= 0) && (row < 112);
#pragma unroll
      for (int cc = 0; cc < 4; ++cc) {
        int col = c0 + cc;
        win[r][cc] = (rv && col >= 0 && col < 112) ? ip[row * 112 + col] : 0.f;
      }
    }
#pragma unroll
    for (int coi = 0; coi < 4; ++coi) {
      const float* wp = w + ((cog * 4 + coi) * 16 + ci) * 9;
      float w00 = wp[0], w01 = wp[1], w02 = wp[2];
      float w10 = wp[3], w11 = wp[4], w12 = wp[5];
      float w20 = wp[6], w21 = wp[7], w22 = wp[8];
#pragma unroll
      for (int dy = 0; dy < 2; ++dy)
#pragma unroll
        for (int dx = 0; dx < 2; ++dx)
          acc[coi][dy * 2 + dx] +=
              win[dy + 0][dx + 0] * w00 + win[dy + 0][dx + 1] * w01 + win[dy + 0][dx + 2] * w02 +
              win[dy + 1][dx + 0] * w10 + win[dy + 1][dx + 1] * w11 + win[dy + 1][dx + 2] * w12 +
              win[dy + 2][dx + 0] * w20 + win[dy + 2][dx + 1] * w21 + win[dy + 2][dx + 2] * w22;
    }
  }
#pragma unroll
  for (int coi = 0; coi < 4; ++coi) {
    int co = cog * 4 + coi;
    float inv  = g[co] * rsqrtf(v[co] + BN_EPS);
    float sh   = bb[co] - m[co] * inv;
    float bias = cb[co];
    float mx = -3.4e38f;
#pragma unroll
    for (int pt = 0; pt < 4; ++pt) {
      float a = (acc[coi][pt] + bias) * inv + sh;
      a = fmaxf(a, 0.f);
      mx = fmaxf(mx, a);
    }
    p2[((b * 32 + co) * 56 + yo) * 56 + xo] = mx;
  }
}

// ------- LDS-staged 3x3 SAME conv on 56x56 + BN + ReLU (conv3 / conv4) -------
// Block = (b, 8-row y-tile, 32-co group). 256 threads = 8 cs x 8 y x 4 xq(14px).
// Per 8-ci chunk: stage input [8][10][58] + weights [8][3][3][32] (co inner,
// float4-aligned). Inner (ci,ky): 16 LDS input reads + 3 float4 weight reads
// -> 168 FMA. Accumulation order matches the R0 kernel (ci asc, ky/kx inner).
template <int CI, int CO>
__global__ __launch_bounds__(256) void k_conv3x3_lds(
    const float* __restrict__ in_, const float* __restrict__ w,
    const float* __restrict__ cb, const float* __restrict__ g,
    const float* __restrict__ bb, const float* __restrict__ m,
    const float* __restrict__ v, float* __restrict__ out_) {
  constexpr int CIC = 8;
  constexpr int NCOG = CO / 32;
  __shared__ float il[CIC][10][58];
  __shared__ __align__(16) float wl[CIC][3][3][32];

  int bid = blockIdx.x;
  int cog = bid % NCOG;
  int yt  = (bid / NCOG) % 7;
  int b   = bid / (NCOG * 7);
  int y0  = yt * 8;

  int tid = threadIdx.x;
  int xq  = tid & 3;          // 4 x-quads of 14 px
  int yy  = (tid >> 2) & 7;   // row within tile
  int cs  = tid >> 5;         // 8 co-subgroups of 4
  int x0  = xq * 14;
  int cs4 = cs * 4;

  float acc[4][14];
#pragma unroll
  for (int i = 0; i < 4; ++i)
#pragma unroll
    for (int j = 0; j < 14; ++j) acc[i][j] = 0.f;

  for (int ci0 = 0; ci0 < CI; ci0 += CIC) {
    __syncthreads();
    // stage input rows y0-1 .. y0+8 (cols -1..56 zero-padded)
    for (int i = tid; i < CIC * 10 * 58; i += 256) {
      int c = i % 58; int t2 = i / 58; int r = t2 % 10; int ci = t2 / 10;
      int gr = y0 - 1 + r, gc = c - 1;
      float val = 0.f;
      if (gr >= 0 && gr < 56 && gc >= 0 && gc < 56)
        val = in_[((size_t)(b * CI + ci0 + ci) * 56 + gr) * 56 + gc];
      il[ci][r][c] = val;
    }
    // stage weights: wl[ci][ky][kx][co], co innermost (flat = i)
    for (int i = tid; i < CIC * 9 * 32; i += 256) {
      int co = i & 31; int t2 = i >> 5; int k = t2 % 9; int ci = t2 / 9;
      ((float*)wl)[i] =
          w[((size_t)(cog * 32 + co) * CI + ci0 + ci) * 9 + k];
    }
    __syncthreads();

    for (int ci = 0; ci < CIC; ++ci) {
#pragma unroll
      for (int ky = 0; ky < 3; ++ky) {
        float r_[16];
#pragma unroll
        for (int i = 0; i < 16; ++i) r_[i] = il[ci][yy + ky][x0 + i];
        float4 w0 = *(const float4*)&wl[ci][ky][0][cs4];
        float4 w1 = *(const float4*)&wl[ci][ky][1][cs4];
        float4 w2 = *(const float4*)&wl[ci][ky][2][cs4];
#pragma unroll
        for (int xi = 0; xi < 14; ++xi) {
          float a0 = r_[xi], a1 = r_[xi + 1], a2 = r_[xi + 2];
          acc[0][xi] += a0 * w0.x + a1 * w1.x + a2 * w2.x;
          acc[1][xi] += a0 * w0.y + a1 * w1.y + a2 * w2.y;
          acc[2][xi] += a0 * w0.z + a1 * w1.z + a2 * w2.z;
          acc[3][xi] += a0 * w0.w + a1 * w1.w + a2 * w2.w;
        }
      }
    }
  }

#pragma unroll
  for (int coi = 0; coi < 4; ++coi) {
    int co = cog * 32 + cs4 + coi;
    float inv  = g[co] * rsqrtf(v[co] + BN_EPS);
    float sh   = bb[co] - m[co] * inv;
    float bias = cb[co];
    float* op = out_ + ((size_t)(b * CO + co) * 56 + (y0 + yy)) * 56 + x0;
#pragma unroll
    for (int xi = 0; xi < 14; ++xi) {
      float a = (acc[coi][xi] + bias) * inv + sh;
      op[xi] = fmaxf(a, 0.f);
    }
  }
}

// --------------------- qconv: 1x1 conv 128->128 + bias -----------------------
// block = (b, 64-pixel tile); stage input tile [128ci][64p] in LDS.
__global__ __launch_bounds__(256) void k_qconv(const float* __restrict__ h4,
                                               const float* __restrict__ wq,
                                               const float* __restrict__ qb,
                                               float* __restrict__ hq) {
  int bi = blockIdx.x / 49;
  int p0 = (blockIdx.x % 49) * 64;
  __shared__ __align__(16) float hl[128][64];
  int tid = threadIdx.x;
  const float* in = h4 + (size_t)bi * 128 * 3136 + p0;
  for (int i = 0; i < 32; ++i) {
    int ci = i * 4 + tid / 64; int p = tid % 64;
    hl[ci][p] = in[ci * 3136 + p];
  }
  __syncthreads();
  int cog = tid / 16;  // 16 groups x 8 co
  int pg  = tid % 16;  // 16 groups x 4 p
  int co0 = cog * 8, pl = pg * 4;
  float acc[8][4];
#pragma unroll
  for (int i = 0; i < 8; ++i)
#pragma unroll
    for (int j = 0; j < 4; ++j) acc[i][j] = 0.f;
  for (int ci = 0; ci < 128; ++ci) {
    float4 hv = *(const float4*)&hl[ci][pl];
#pragma unroll
    for (int coi = 0; coi < 8; ++coi) {
      float wv = wq[(co0 + coi) * 128 + ci];
      acc[coi][0] += hv.x * wv; acc[coi][1] += hv.y * wv;
      acc[coi][2] += hv.z * wv; acc[coi][3] += hv.w * wv;
    }
  }
#pragma unroll
  for (int coi = 0; coi < 8; ++coi) {
    float bias = qb[co0 + coi];
    float* op = hq + ((size_t)bi * 128 + co0 + coi) * 3136 + p0 + pl;
#pragma unroll
    for (int xi = 0; xi < 4; ++xi) op[xi] = acc[coi][xi] + bias;
  }
}

// --------------- VQ: argmin_c ( enorm[c] - 2 * <flat_n, embed_c> ) -----------
// ||flat||^2 omitted (argmin-invariant). block = 64-point tile; codes chunked
// by 64 with embed chunk in LDS [d][c] (natural orientation, conflict-free).
// thread tile: 4 points x 4 codes; code id c = cg + 16*ci (strided for banks).
__global__ __launch_bounds__(256) void k_vq_argmin(const float* __restrict__ hq,
                                                   const float* __restrict__ embed,
                                                   const float* __restrict__ enorm,
                                                   int* __restrict__ ind) {
  int bi = blockIdx.x / 49;
  int p0 = (blockIdx.x % 49) * 64;
  __shared__ __align__(16) float fl[64][132];  // [p][d], pad 132
  __shared__ __align__(16) float el[128][64];  // [d][c]
  int tid = threadIdx.x;
  const float* in = hq + (size_t)bi * 128 * 3136 + p0;
  for (int i = 0; i < 32; ++i) {
    int d = i * 4 + tid / 64; int p = tid % 64;
    fl[p][d] = in[d * 3136 + p];
  }
  int cg = tid % 16;  // code group (lanes 0..15 consecutive)
  int pg = tid / 16;  // point group (4 points)
  float best[4]; int bidx[4];
#pragma unroll
  for (int i = 0; i < 4; ++i) { best[i] = 3.4e38f; bidx[i] = 0; }

  for (int cc = 0; cc < 16; ++cc) {
    __syncthreads();  // also covers fl on first iteration
    for (int i = 0; i < 32; ++i) {
      int d = i * 4 + tid / 64; int c = tid % 64;
      el[d][c] = embed[d * 1024 + cc * 64 + c];
    }
    __syncthreads();
    float acc[4][4];
#pragma unroll
    for (int i = 0; i < 4; ++i)
#pragma unroll
      for (int j = 0; j < 4; ++j) acc[i][j] = 0.f;

#pragma unroll 2
    for (int d = 0; d < 128; d += 4) {
      const float4 f0 = *(const float4*)&fl[pg * 4 + 0][d];
      const float4 f1 = *(const float4*)&fl[pg * 4 + 1][d];
      const float4 f2 = *(const float4*)&fl[pg * 4 + 2][d];
      const float4 f3 = *(const float4*)&fl[pg * 4 + 3][d];
#pragma unroll
      for (int ci = 0; ci < 4; ++ci) {
        const int c = cg + 16 * ci;
        const float e0 = el[d + 0][c];
        const float e1 = el[d + 1][c];
        const float e2 = el[d + 2][c];
        const float e3 = el[d + 3][c];
        acc[0][ci] += f0.x * e0 + f0.y * e1 + f0.z * e2 + f0.w * e3;
        acc[1][ci] += f1.x * e0 + f1.y * e1 + f1.z * e2 + f1.w * e3;
        acc[2][ci] += f2.x * e0 + f2.y * e1 + f2.z * e2 + f2.w * e3;
        acc[3][ci] += f3.x * e0 + f3.y * e1 + f3.z * e2 + f3.w * e3;
      }
    }
#pragma unroll
    for (int pi = 0; pi < 4; ++pi)
#pragma unroll
      for (int ci = 0; ci < 4; ++ci) {
        int c = cc * 64 + cg + 16 * ci;
        float dist = enorm[c] - 2.f * acc[pi][ci];
        // strict < keeps earliest index (per-thread candidates ascend in c)
        if (dist < best[pi]) { best[pi] = dist; bidx[pi] = c; }
      }
  }
  // reduce across the 16 cg lanes (consecutive); first-min tie-break
#pragma unroll
  for (int pi = 0; pi < 4; ++pi) {
    float b_ = best[pi]; int x_ = bidx[pi];
    for (int off = 8; off >= 1; off >>= 1) {
      float ob = __shfl_xor(b_, off);
      int   ox = __shfl_xor(x_, off);
      if (ob < b_ || (ob == b_ && ox < x_)) { b_ = ob; x_ = ox; }
    }
    if (cg == 0) ind[bi * 3136 + p0 + pg * 4 + pi] = x_;
  }
}

// ------ gather codes to NCHW (qn) + per-block sum of (q-h)^2 into bsum -------
__global__ __launch_bounds__(256) void k_gather_diff(const float* __restrict__ hq,
                                                     const float* __restrict__ embed,
                                                     const int* __restrict__ ind,
                                                     float* __restrict__ qn,
                                                     float* __restrict__ bsum) {
  int gid = blockIdx.x * 256 + threadIdx.x;  // over [b][d][p] flat
  int p = gid % 3136; int t = gid / 3136; int d = t % 128; int b = t / 128;
  int idx = ind[b * 3136 + p];
  float q = embed[d * 1024 + idx];
  float h = hq[gid];
  qn[gid] = q;
  float df = q - h;
  float val = df * df;
  for (int off = 32; off >= 1; off >>= 1) val += __shfl_down(val, off);
  __shared__ float red[4];
  int lane = threadIdx.x & 63, wv = threadIdx.x >> 6;
  if (lane == 0) red[wv] = val;
  __syncthreads();
  if (threadIdx.x == 0) bsum[blockIdx.x] = red[0] + red[1] + red[2] + red[3];
}

// ------------------- fc1 split-K partials: z_pre = qn @ w^T ------------------
// 784 blocks x K-span 512; LDS tiles ql[32][64], wl[128][64] (XOR-swizzled);
// thread tile 4b x 4j with strided ids (b = bg+8*bi, j = jg+32*ji) for banks.
__global__ __launch_bounds__(256) void k_fc1(const float* __restrict__ qn,
                                             const float* __restrict__ w,
                                             float* __restrict__ part) {
  int kb = blockIdx.x;
  int k0 = kb * 512;
  __shared__ __align__(16) float ql[32][64];
  __shared__ __align__(16) float wl[128][64];
  int tid = threadIdx.x;
  int bg = tid / 32, jg = tid % 32;
  float acc[4][4];
#pragma unroll
  for (int i = 0; i < 4; ++i)
#pragma unroll
    for (int j = 0; j < 4; ++j) acc[i][j] = 0.f;

  for (int kt = 0; kt < 512; kt += 64) {
    __syncthreads();
#pragma unroll
    for (int i = 0; i < 8; ++i) {
      int b = i * 4 + tid / 64; int k = tid % 64;
      ql[b][k ^ ((b & 15) << 2)] = qn[(size_t)b * 401408 + k0 + kt + k];
    }
#pragma unroll 4
    for (int i = 0; i < 32; ++i) {
      int j = i * 4 + tid / 64; int k = tid % 64;
      wl[j][k ^ ((j & 15) << 2)] = w[(size_t)j * 401408 + k0 + kt + k];
    }
    __syncthreads();
    for (int k = 0; k < 64; k += 4) {
      float4 qv[4], wv[4];
#pragma unroll
      for (int bi = 0; bi < 4; ++bi) {
        int b = bg + 8 * bi;
        qv[bi] = *(const float4*)&ql[b][k ^ ((b & 15) << 2)];
      }
#pragma unroll
      for (int ji = 0; ji < 4; ++ji) {
        int j = jg + 32 * ji;
        wv[ji] = *(const float4*)&wl[j][k ^ ((j & 15) << 2)];
      }
#pragma unroll
      for (int bi = 0; bi < 4; ++bi)
#pragma unroll
        for (int ji = 0; ji < 4; ++ji)
          acc[bi][ji] += qv[bi].x * wv[ji].x + qv[bi].y * wv[ji].y +
                         qv[bi].z * wv[ji].z + qv[bi].w * wv[ji].w;
    }
  }
#pragma unroll
  for (int bi = 0; bi < 4; ++bi)
#pragma unroll
    for (int ji = 0; ji < 4; ++ji)
      part[(size_t)kb * 4096 + (bg + 8 * bi) * 128 + (jg + 32 * ji)] = acc[bi][ji];
}

// --------------- reduce split-K partials, add bias, leaky_relu ---------------
__global__ __launch_bounds__(256) void k_fc1_reduce(const float* __restrict__ part,
                                                    const float* __restrict__ fb,
                                                    float* __restrict__ z) {
  int t = blockIdx.x * 256 + threadIdx.x;  // 4096 = 32b x 128j
  if (t >= 4096) return;
  float s = 0.f;
  for (int i = 0; i < 784; ++i) s += part[(size_t)i * 4096 + t];
  s += fb[t % 128];
  z[t] = (s > 0.f) ? s : 0.01f * s;
}

// ---------- head: fc2 + log_softmax + diff finalize (single block) -----------
__global__ __launch_bounds__(384) void k_head(const float* __restrict__ z,
                                              const float* __restrict__ w2,
                                              const float* __restrict__ b2,
                                              const float* __restrict__ bsum,
                                              float* __restrict__ out) {
  __shared__ float lg[32][11];
  __shared__ float lse[32];
  __shared__ float sred[384];
  int t = threadIdx.x;

  // diff partial-sum reduction (50176 block sums)
  float s = 0.f;
  for (int i = t; i < 50176; i += 384) s += bsum[i];
  sred[t] = s;
  __syncthreads();
  if (t < 128) sred[t] += sred[t + 128] + sred[t + 256];
  __syncthreads();
  for (int st = 64; st >= 1; st >>= 1) {
    if (t < st) sred[t] += sred[t + st];
    __syncthreads();
  }

  // logits
  if (t < 352) {
    int b = t / 11, j = t % 11;
    float acc = b2[j];
    for (int d = 0; d < 128; ++d) acc += z[b * 128 + d] * w2[j * 128 + d];
    lg[b][j] = acc;
  }
  __syncthreads();
  if (t < 32) {
    float mx = -3.4e38f;
    for (int j = 0; j < 11; ++j) mx = fmaxf(mx, lg[t][j]);
    float se = 0.f;
    for (int j = 0; j < 11; ++j) se += expf(lg[t][j] - mx);
    lse[t] = mx + logf(se);
  }
  __syncthreads();
  if (t < 352) { int b = t / 11, j = t % 11; out[t] = lg[b][j] - lse[b]; }
  if (t == 352) out[352] = 1.25f * sred[0] / 12845056.0f;
}

// ---------------------------------------------------------------------------
extern "C" void kernel_launch(void* const* d_in, const int* in_sizes, int n_in,
                              void* d_out, int out_size, void* d_ws, size_t ws_size,
                              hipStream_t stream) {
  const float* x    = (const float*)d_in[0];
  const float* c1w  = (const float*)d_in[1];
  const float* c1b  = (const float*)d_in[2];
  const float* c2w  = (const float*)d_in[3];
  const float* c2b  = (const float*)d_in[4];
  const float* c3w  = (const float*)d_in[5];
  const float* c3b  = (const float*)d_in[6];
  const float* c4w  = (const float*)d_in[7];
  const float* c4b  = (const float*)d_in[8];
  const float* bn1g = (const float*)d_in[9];
  const float* bn1b = (const float*)d_in[10];
  const float* bn1m = (const float*)d_in[11];
  const float* bn1v = (const float*)d_in[12];
  const float* bn2g = (const float*)d_in[13];
  const float* bn2b = (const float*)d_in[14];
  const float* bn2m = (const float*)d_in[15];
  const float* bn2v = (const float*)d_in[16];
  const float* bn3g = (const float*)d_in[17];
  const float* bn3b = (const float*)d_in[18];
  const float* bn3m = (const float*)d_in[19];
  const float* bn3v = (const float*)d_in[20];
  const float* bn4g = (const float*)d_in[21];
  const float* bn4b = (const float*)d_in[22];
  const float* bn4m = (const float*)d_in[23];
  const float* bn4v = (const float*)d_in[24];
  const float* qw   = (const float*)d_in[25];
  const float* qcb  = (const float*)d_in[26];
  const float* emb  = (const float*)d_in[27];
  const float* f1w  = (const float*)d_in[28];
  const float* f1b  = (const float*)d_in[29];
  const float* f2w  = (const float*)d_in[30];
  const float* f2b  = (const float*)d_in[31];

  float* ws  = (float*)d_ws;
  float* out = (float*)d_out;

  float* p1   = ws + OFF_P1;
  float* p2   = ws + OFF_P2;
  float* h3   = ws + OFF_H3;
  float* h4   = ws + OFF_H4;
  float* hq   = ws + OFF_HQ;
  float* qn   = ws + OFF_QN;
  int*   ind  = (int*)(ws + OFF_IND);
  float* en   = ws + OFF_EN;
  float* part = ws + OFF_PART;
  float* z    = ws + OFF_Z;
  float* bsum = ws + OFF_BSUM;

  k_enorm<<<4, 256, 0, stream>>>(emb, en);
  k_conv1_pool<<<25088, 256, 0, stream>>>(x, c1w, c1b, bn1g, bn1b, bn1m, bn1v, p1);
  k_conv2_pool<<<3136, 256, 0, stream>>>(p1, c2w, c2b, bn2g, bn2b, bn2m, bn2v, p2);
  // conv3: CO=64 -> 2 co-groups; grid = 32 b * 7 ytiles * 2 = 448
  k_conv3x3_lds<32, 64><<<448, 256, 0, stream>>>(p2, c3w, c3b, bn3g, bn3b, bn3m, bn3v, h3);
  // conv4: CO=128 -> 4 co-groups; grid = 32 * 7 * 4 = 896
  k_conv3x3_lds<64, 128><<<896, 256, 0, stream>>>(h3, c4w, c4b, bn4g, bn4b, bn4m, bn4v, h4);
  k_qconv<<<1568, 256, 0, stream>>>(h4, qw, qcb, hq);
  k_vq_argmin<<<1568, 256, 0, stream>>>(hq, emb, en, ind);
  k_gather_diff<<<50176, 256, 0, stream>>>(hq, emb, ind, qn, bsum);
  k_fc1<<<784, 256, 0, stream>>>(qn, f1w, part);
  k_fc1_reduce<<<16, 256, 0, stream>>>(part, f1b, z);
  k_head<<<1, 384, 0, stream>>>(z, f2w, f2b, bsum, out);
}

// Round 5
// 1642.781 us; speedup vs baseline: 1.6632x; 1.0568x over previous
//
#include <hip/hip_runtime.h>
#include <math.h>

// ---------------------------------------------------------------------------
// VQ-VAE eval forward: conv stack -> 1x1 conv -> VQ (argmin codebook) ->
// classifier head. All fp32 (CDNA4 has no fp32 MFMA; vector ALU).
// R1: conv3/conv4 LDS-staged tiles. MEASURED R4: 2732 -> 1736 us, conv gone
//     from top-5.
// R5: vq_argmin inner loop was LDS-read-bound (16 scalar el reads / 64 FMA;
//     VALUBusy 63%). Codes now 4-consecutive per thread -> el reads become
//     float4 (8x ds_read_b128 / 64 FMA = 96 cyc LDS vs 128 cyc VALU).
//     fl pad 132 -> 140 (float4-aligned rows, conflict-free broadcast reads).
//     Numerics bit-identical (same d-order FMA chains per (p,c)).
// Workspace layout (float offsets), aggressive buffer reuse, ~155 MB:
//   p1  [32,16,112,112]  @ 0          (6,422,528)
//   p2  [32,32,56,56]    @ 6,422,528  (3,211,264)
//   h3  [32,64,56,56]    @ 0          (reuses p1, dead)
//   h4  [32,128,56,56]   @ 9,633,792  (12,845,056)
//   hq  [32,128,56,56]   @ 22,478,848 (12,845,056)
//   qn  [32,128,56,56]   @ 0          (reuses h3/p2/h4-prefix, all dead)
//   ind [100352] int     @ 35,323,904
//   enorm [1024]         @ 35,424,256
//   part [784*4096]      @ 35,425,536
//   z    [4096]          @ 38,636,800
//   bsum [50176]         @ 38,640,896   -> end 38,691,072 floats (~154.8 MB)
// ---------------------------------------------------------------------------

#define OFF_P1    0u
#define OFF_P2    6422528u
#define OFF_H3    0u
#define OFF_H4    9633792u
#define OFF_HQ    22478848u
#define OFF_QN    0u
#define OFF_IND   35323904u
#define OFF_EN    35424256u
#define OFF_PART  35425536u
#define OFF_Z     38636800u
#define OFF_BSUM  38640896u

#define BN_EPS 1e-5f

// ---------------- embed norms: enorm[c] = sum_d embed[d][c]^2 ----------------
__global__ __launch_bounds__(256) void k_enorm(const float* __restrict__ embed,
                                               float* __restrict__ enorm) {
  int c = blockIdx.x * 256 + threadIdx.x;
  if (c < 1024) {
    float s = 0.f;
    for (int d = 0; d < 128; ++d) { float e = embed[d * 1024 + c]; s += e * e; }
    enorm[c] = s;
  }
}

// ------------- conv1 (1->16, 3x3 SAME) + BN + ReLU + 2x2 maxpool -------------
// one thread = one pooled output (b, c, yo, xo); reads 4x4 input window.
__global__ __launch_bounds__(256) void k_conv1_pool(
    const float* __restrict__ x, const float* __restrict__ w,
    const float* __restrict__ cb, const float* __restrict__ g,
    const float* __restrict__ bb, const float* __restrict__ m,
    const float* __restrict__ v, float* __restrict__ p1) {
  int gid = blockIdx.x * 256 + threadIdx.x;
  if (gid >= 32 * 16 * 112 * 112) return;
  int xo = gid % 112; int t = gid / 112;
  int yo = t % 112;  t /= 112;
  int c = t % 16;    int b = t / 16;

  float wreg[9];
#pragma unroll
  for (int i = 0; i < 9; ++i) wreg[i] = w[c * 9 + i];
  float inv  = g[c] * rsqrtf(v[c] + BN_EPS);
  float sh   = bb[c] - m[c] * inv;
  float bias = cb[c];

  const float* xb = x + b * 224 * 224;
  int r0 = 2 * yo - 1, c0 = 2 * xo - 1;
  float win[4][4];
#pragma unroll
  for (int r = 0; r < 4; ++r) {
    int row = r0 + r;
    bool rv = (row >= 0) && (row < 224);
#pragma unroll
    for (int cc = 0; cc < 4; ++cc) {
      int col = c0 + cc;
      win[r][cc] = (rv && col >= 0 && col < 224) ? xb[row * 224 + col] : 0.f;
    }
  }
  float mx = -3.4e38f;
#pragma unroll
  for (int dy = 0; dy < 2; ++dy)
#pragma unroll
    for (int dx = 0; dx < 2; ++dx) {
      float a = bias;
#pragma unroll
      for (int ky = 0; ky < 3; ++ky)
#pragma unroll
        for (int kx = 0; kx < 3; ++kx)
          a += win[dy + ky][dx + kx] * wreg[ky * 3 + kx];
      a = a * inv + sh;
      a = fmaxf(a, 0.f);
      mx = fmaxf(mx, a);
    }
  p1[gid] = mx;  // gid ordering == [b][c][yo][xo] flat
}

// ------------- conv2 (16->32) + BN + ReLU + pool; 4 co per thread -------------
__global__ __launch_bounds__(256) void k_conv2_pool(
    const float* __restrict__ p1, const float* __restrict__ w,
    const float* __restrict__ cb, const float* __restrict__ g,
    const float* __restrict__ bb, const float* __restrict__ m,
    const float* __restrict__ v, float* __restrict__ p2) {
  int gid = blockIdx.x * 256 + threadIdx.x;
  if (gid >= 32 * 8 * 56 * 56) return;
  int xo = gid % 56; int t = gid / 56;
  int yo = t % 56;  t /= 56;
  int cog = t % 8;  int b = t / 8;

  float acc[4][4];  // [coi][dy*2+dx]
#pragma unroll
  for (int i = 0; i < 4; ++i)
#pragma unroll
    for (int j = 0; j < 4; ++j) acc[i][j] = 0.f;

  const float* in = p1 + b * 16 * 112 * 112;
  int r0 = 2 * yo - 1, c0 = 2 * xo - 1;
  for (int ci = 0; ci < 16; ++ci) {
    const float* ip = in + ci * 112 * 112;
    float win[4][4];
#pragma unroll
    for (int r = 0; r < 4; ++r) {
      int row = r0 + r;
      bool rv = (row >= 0) && (row < 112);
#pragma unroll
      for (int cc = 0; cc < 4; ++cc) {
        int col = c0 + cc;
        win[r][cc] = (rv && col >= 0 && col < 112) ? ip[row * 112 + col] : 0.f;
      }
    }
#pragma unroll
    for (int coi = 0; coi < 4; ++coi) {
      const float* wp = w + ((cog * 4 + coi) * 16 + ci) * 9;
      float w00 = wp[0], w01 = wp[1], w02 = wp[2];
      float w10 = wp[3], w11 = wp[4], w12 = wp[5];
      float w20 = wp[6], w21 = wp[7], w22 = wp[8];
#pragma unroll
      for (int dy = 0; dy < 2; ++dy)
#pragma unroll
        for (int dx = 0; dx < 2; ++dx)
          acc[coi][dy * 2 + dx] +=
              win[dy + 0][dx + 0] * w00 + win[dy + 0][dx + 1] * w01 + win[dy + 0][dx + 2] * w02 +
              win[dy + 1][dx + 0] * w10 + win[dy + 1][dx + 1] * w11 + win[dy + 1][dx + 2] * w12 +
              win[dy + 2][dx + 0] * w20 + win[dy + 2][dx + 1] * w21 + win[dy + 2][dx + 2] * w22;
    }
  }
#pragma unroll
  for (int coi = 0; coi < 4; ++coi) {
    int co = cog * 4 + coi;
    float inv  = g[co] * rsqrtf(v[co] + BN_EPS);
    float sh   = bb[co] - m[co] * inv;
    float bias = cb[co];
    float mx = -3.4e38f;
#pragma unroll
    for (int pt = 0; pt < 4; ++pt) {
      float a = (acc[coi][pt] + bias) * inv + sh;
      a = fmaxf(a, 0.f);
      mx = fmaxf(mx, a);
    }
    p2[((b * 32 + co) * 56 + yo) * 56 + xo] = mx;
  }
}

// ------- LDS-staged 3x3 SAME conv on 56x56 + BN + ReLU (conv3 / conv4) -------
// Block = (b, 8-row y-tile, 32-co group). 256 threads = 8 cs x 8 y x 4 xq(14px).
// Per 8-ci chunk: stage input [8][10][58] + weights [8][3][3][32] (co inner,
// float4-aligned). Inner (ci,ky): 16 LDS input reads + 3 float4 weight reads
// -> 168 FMA. Accumulation order matches the R0 kernel (ci asc, ky/kx inner).
template <int CI, int CO>
__global__ __launch_bounds__(256) void k_conv3x3_lds(
    const float* __restrict__ in_, const float* __restrict__ w,
    const float* __restrict__ cb, const float* __restrict__ g,
    const float* __restrict__ bb, const float* __restrict__ m,
    const float* __restrict__ v, float* __restrict__ out_) {
  constexpr int CIC = 8;
  constexpr int NCOG = CO / 32;
  __shared__ float il[CIC][10][58];
  __shared__ __align__(16) float wl[CIC][3][3][32];

  int bid = blockIdx.x;
  int cog = bid % NCOG;
  int yt  = (bid / NCOG) % 7;
  int b   = bid / (NCOG * 7);
  int y0  = yt * 8;

  int tid = threadIdx.x;
  int xq  = tid & 3;          // 4 x-quads of 14 px
  int yy  = (tid >> 2) & 7;   // row within tile
  int cs  = tid >> 5;         // 8 co-subgroups of 4
  int x0  = xq * 14;
  int cs4 = cs * 4;

  float acc[4][14];
#pragma unroll
  for (int i = 0; i < 4; ++i)
#pragma unroll
    for (int j = 0; j < 14; ++j) acc[i][j] = 0.f;

  for (int ci0 = 0; ci0 < CI; ci0 += CIC) {
    __syncthreads();
    // stage input rows y0-1 .. y0+8 (cols -1..56 zero-padded)
    for (int i = tid; i < CIC * 10 * 58; i += 256) {
      int c = i % 58; int t2 = i / 58; int r = t2 % 10; int ci = t2 / 10;
      int gr = y0 - 1 + r, gc = c - 1;
      float val = 0.f;
      if (gr >= 0 && gr < 56 && gc >= 0 && gc < 56)
        val = in_[((size_t)(b * CI + ci0 + ci) * 56 + gr) * 56 + gc];
      il[ci][r][c] = val;
    }
    // stage weights: wl[ci][ky][kx][co], co innermost (flat = i)
    for (int i = tid; i < CIC * 9 * 32; i += 256) {
      int co = i & 31; int t2 = i >> 5; int k = t2 % 9; int ci = t2 / 9;
      ((float*)wl)[i] =
          w[((size_t)(cog * 32 + co) * CI + ci0 + ci) * 9 + k];
    }
    __syncthreads();

    for (int ci = 0; ci < CIC; ++ci) {
#pragma unroll
      for (int ky = 0; ky < 3; ++ky) {
        float r_[16];
#pragma unroll
        for (int i = 0; i < 16; ++i) r_[i] = il[ci][yy + ky][x0 + i];
        float4 w0 = *(const float4*)&wl[ci][ky][0][cs4];
        float4 w1 = *(const float4*)&wl[ci][ky][1][cs4];
        float4 w2 = *(const float4*)&wl[ci][ky][2][cs4];
#pragma unroll
        for (int xi = 0; xi < 14; ++xi) {
          float a0 = r_[xi], a1 = r_[xi + 1], a2 = r_[xi + 2];
          acc[0][xi] += a0 * w0.x + a1 * w1.x + a2 * w2.x;
          acc[1][xi] += a0 * w0.y + a1 * w1.y + a2 * w2.y;
          acc[2][xi] += a0 * w0.z + a1 * w1.z + a2 * w2.z;
          acc[3][xi] += a0 * w0.w + a1 * w1.w + a2 * w2.w;
        }
      }
    }
  }

#pragma unroll
  for (int coi = 0; coi < 4; ++coi) {
    int co = cog * 32 + cs4 + coi;
    float inv  = g[co] * rsqrtf(v[co] + BN_EPS);
    float sh   = bb[co] - m[co] * inv;
    float bias = cb[co];
    float* op = out_ + ((size_t)(b * CO + co) * 56 + (y0 + yy)) * 56 + x0;
#pragma unroll
    for (int xi = 0; xi < 14; ++xi) {
      float a = (acc[coi][xi] + bias) * inv + sh;
      op[xi] = fmaxf(a, 0.f);
    }
  }
}

// --------------------- qconv: 1x1 conv 128->128 + bias -----------------------
// block = (b, 64-pixel tile); stage input tile [128ci][64p] in LDS.
__global__ __launch_bounds__(256) void k_qconv(const float* __restrict__ h4,
                                               const float* __restrict__ wq,
                                               const float* __restrict__ qb,
                                               float* __restrict__ hq) {
  int bi = blockIdx.x / 49;
  int p0 = (blockIdx.x % 49) * 64;
  __shared__ __align__(16) float hl[128][64];
  int tid = threadIdx.x;
  const float* in = h4 + (size_t)bi * 128 * 3136 + p0;
  for (int i = 0; i < 32; ++i) {
    int ci = i * 4 + tid / 64; int p = tid % 64;
    hl[ci][p] = in[ci * 3136 + p];
  }
  __syncthreads();
  int cog = tid / 16;  // 16 groups x 8 co
  int pg  = tid % 16;  // 16 groups x 4 p
  int co0 = cog * 8, pl = pg * 4;
  float acc[8][4];
#pragma unroll
  for (int i = 0; i < 8; ++i)
#pragma unroll
    for (int j = 0; j < 4; ++j) acc[i][j] = 0.f;
  for (int ci = 0; ci < 128; ++ci) {
    float4 hv = *(const float4*)&hl[ci][pl];
#pragma unroll
    for (int coi = 0; coi < 8; ++coi) {
      float wv = wq[(co0 + coi) * 128 + ci];
      acc[coi][0] += hv.x * wv; acc[coi][1] += hv.y * wv;
      acc[coi][2] += hv.z * wv; acc[coi][3] += hv.w * wv;
    }
  }
#pragma unroll
  for (int coi = 0; coi < 8; ++coi) {
    float bias = qb[co0 + coi];
    float* op = hq + ((size_t)bi * 128 + co0 + coi) * 3136 + p0 + pl;
#pragma unroll
    for (int xi = 0; xi < 4; ++xi) op[xi] = acc[coi][xi] + bias;
  }
}

// --------------- VQ: argmin_c ( enorm[c] - 2 * <flat_n, embed_c> ) -----------
// ||flat||^2 omitted (argmin-invariant). block = 64-point tile; codes chunked
// by 64 with embed chunk in LDS [d][c] (natural orientation). R5: thread tile
// 4 points x 4 CONSECUTIVE codes (c = cc*64 + cg*4 + ci) so el reads are
// aligned float4 -> inner loop is 8x ds_read_b128 per 64 FMA (VALU-bound).
// fl pad = 140 floats (560 B rows: float4-aligned; 4-row stride = 16 mod 32
// banks -> broadcast reads conflict-free).
__global__ __launch_bounds__(256) void k_vq_argmin(const float* __restrict__ hq,
                                                   const float* __restrict__ embed,
                                                   const float* __restrict__ enorm,
                                                   int* __restrict__ ind) {
  int bi = blockIdx.x / 49;
  int p0 = (blockIdx.x % 49) * 64;
  __shared__ __align__(16) float fl[64][140];  // [p][d]
  __shared__ __align__(16) float el[128][64];  // [d][c]
  int tid = threadIdx.x;
  const float* in = hq + (size_t)bi * 128 * 3136 + p0;
  for (int i = 0; i < 32; ++i) {
    int d = i * 4 + tid / 64; int p = tid % 64;
    fl[p][d] = in[d * 3136 + p];
  }
  int cg = tid % 16;  // code group: 4 consecutive codes at cg*4
  int pg = tid / 16;  // point group: 4 points at pg*4
  float best[4]; int bidx[4];
#pragma unroll
  for (int i = 0; i < 4; ++i) { best[i] = 3.4e38f; bidx[i] = 0; }

  for (int cc = 0; cc < 16; ++cc) {
    __syncthreads();  // also covers fl on first iteration
    for (int i = 0; i < 32; ++i) {
      int d = i * 4 + tid / 64; int c = tid % 64;
      el[d][c] = embed[d * 1024 + cc * 64 + c];
    }
    __syncthreads();
    float acc[4][4];  // [pi][ci]
#pragma unroll
    for (int i = 0; i < 4; ++i)
#pragma unroll
      for (int j = 0; j < 4; ++j) acc[i][j] = 0.f;

#pragma unroll 2
    for (int d = 0; d < 128; d += 4) {
      const float4 f0 = *(const float4*)&fl[pg * 4 + 0][d];
      const float4 f1 = *(const float4*)&fl[pg * 4 + 1][d];
      const float4 f2 = *(const float4*)&fl[pg * 4 + 2][d];
      const float4 f3 = *(const float4*)&fl[pg * 4 + 3][d];
      const float4 e0 = *(const float4*)&el[d + 0][cg * 4];
      const float4 e1 = *(const float4*)&el[d + 1][cg * 4];
      const float4 e2 = *(const float4*)&el[d + 2][cg * 4];
      const float4 e3 = *(const float4*)&el[d + 3][cg * 4];
      // acc[pi][ci] += sum_k f_pi[k] * el[d+k][cg*4+ci]  (same chain as R0)
      acc[0][0] += f0.x * e0.x + f0.y * e1.x + f0.z * e2.x + f0.w * e3.x;
      acc[0][1] += f0.x * e0.y + f0.y * e1.y + f0.z * e2.y + f0.w * e3.y;
      acc[0][2] += f0.x * e0.z + f0.y * e1.z + f0.z * e2.z + f0.w * e3.z;
      acc[0][3] += f0.x * e0.w + f0.y * e1.w + f0.z * e2.w + f0.w * e3.w;
      acc[1][0] += f1.x * e0.x + f1.y * e1.x + f1.z * e2.x + f1.w * e3.x;
      acc[1][1] += f1.x * e0.y + f1.y * e1.y + f1.z * e2.y + f1.w * e3.y;
      acc[1][2] += f1.x * e0.z + f1.y * e1.z + f1.z * e2.z + f1.w * e3.z;
      acc[1][3] += f1.x * e0.w + f1.y * e1.w + f1.z * e2.w + f1.w * e3.w;
      acc[2][0] += f2.x * e0.x + f2.y * e1.x + f2.z * e2.x + f2.w * e3.x;
      acc[2][1] += f2.x * e0.y + f2.y * e1.y + f2.z * e2.y + f2.w * e3.y;
      acc[2][2] += f2.x * e0.z + f2.y * e1.z + f2.z * e2.z + f2.w * e3.z;
      acc[2][3] += f2.x * e0.w + f2.y * e1.w + f2.z * e2.w + f2.w * e3.w;
      acc[3][0] += f3.x * e0.x + f3.y * e1.x + f3.z * e2.x + f3.w * e3.x;
      acc[3][1] += f3.x * e0.y + f3.y * e1.y + f3.z * e2.y + f3.w * e3.y;
      acc[3][2] += f3.x * e0.z + f3.y * e1.z + f3.z * e2.z + f3.w * e3.z;
      acc[3][3] += f3.x * e0.w + f3.y * e1.w + f3.z * e2.w + f3.w * e3.w;
    }
#pragma unroll
    for (int pi = 0; pi < 4; ++pi)
#pragma unroll
      for (int ci = 0; ci < 4; ++ci) {
        int c = cc * 64 + cg * 4 + ci;
        float dist = enorm[c] - 2.f * acc[pi][ci];
        // strict < keeps earliest index (per-thread candidates ascend in c)
        if (dist < best[pi]) { best[pi] = dist; bidx[pi] = c; }
      }
  }
  // reduce across the 16 cg lanes; first-min tie-break (disjoint c ranges)
#pragma unroll
  for (int pi = 0; pi < 4; ++pi) {
    float b_ = best[pi]; int x_ = bidx[pi];
    for (int off = 8; off >= 1; off >>= 1) {
      float ob = __shfl_xor(b_, off);
      int   ox = __shfl_xor(x_, off);
      if (ob < b_ || (ob == b_ && ox < x_)) { b_ = ob; x_ = ox; }
    }
    if (cg == 0) ind[bi * 3136 + p0 + pg * 4 + pi] = x_;
  }
}

// ------ gather codes to NCHW (qn) + per-block sum of (q-h)^2 into bsum -------
__global__ __launch_bounds__(256) void k_gather_diff(const float* __restrict__ hq,
                                                     const float* __restrict__ embed,
                                                     const int* __restrict__ ind,
                                                     float* __restrict__ qn,
                                                     float* __restrict__ bsum) {
  int gid = blockIdx.x * 256 + threadIdx.x;  // over [b][d][p] flat
  int p = gid % 3136; int t = gid / 3136; int d = t % 128; int b = t / 128;
  int idx = ind[b * 3136 + p];
  float q = embed[d * 1024 + idx];
  float h = hq[gid];
  qn[gid] = q;
  float df = q - h;
  float val = df * df;
  for (int off = 32; off >= 1; off >>= 1) val += __shfl_down(val, off);
  __shared__ float red[4];
  int lane = threadIdx.x & 63, wv = threadIdx.x >> 6;
  if (lane == 0) red[wv] = val;
  __syncthreads();
  if (threadIdx.x == 0) bsum[blockIdx.x] = red[0] + red[1] + red[2] + red[3];
}

// ------------------- fc1 split-K partials: z_pre = qn @ w^T ------------------
// 784 blocks x K-span 512; LDS tiles ql[32][64], wl[128][64] (XOR-swizzled);
// thread tile 4b x 4j with strided ids (b = bg+8*bi, j = jg+32*ji) for banks.
__global__ __launch_bounds__(256) void k_fc1(const float* __restrict__ qn,
                                             const float* __restrict__ w,
                                             float* __restrict__ part) {
  int kb = blockIdx.x;
  int k0 = kb * 512;
  __shared__ __align__(16) float ql[32][64];
  __shared__ __align__(16) float wl[128][64];
  int tid = threadIdx.x;
  int bg = tid / 32, jg = tid % 32;
  float acc[4][4];
#pragma unroll
  for (int i = 0; i < 4; ++i)
#pragma unroll
    for (int j = 0; j < 4; ++j) acc[i][j] = 0.f;

  for (int kt = 0; kt < 512; kt += 64) {
    __syncthreads();
#pragma unroll
    for (int i = 0; i < 8; ++i) {
      int b = i * 4 + tid / 64; int k = tid % 64;
      ql[b][k ^ ((b & 15) << 2)] = qn[(size_t)b * 401408 + k0 + kt + k];
    }
#pragma unroll 4
    for (int i = 0; i < 32; ++i) {
      int j = i * 4 + tid / 64; int k = tid % 64;
      wl[j][k ^ ((j & 15) << 2)] = w[(size_t)j * 401408 + k0 + kt + k];
    }
    __syncthreads();
    for (int k = 0; k < 64; k += 4) {
      float4 qv[4], wv[4];
#pragma unroll
      for (int bi = 0; bi < 4; ++bi) {
        int b = bg + 8 * bi;
        qv[bi] = *(const float4*)&ql[b][k ^ ((b & 15) << 2)];
      }
#pragma unroll
      for (int ji = 0; ji < 4; ++ji) {
        int j = jg + 32 * ji;
        wv[ji] = *(const float4*)&wl[j][k ^ ((j & 15) << 2)];
      }
#pragma unroll
      for (int bi = 0; bi < 4; ++bi)
#pragma unroll
        for (int ji = 0; ji < 4; ++ji)
          acc[bi][ji] += qv[bi].x * wv[ji].x + qv[bi].y * wv[ji].y +
                         qv[bi].z * wv[ji].z + qv[bi].w * wv[ji].w;
    }
  }
#pragma unroll
  for (int bi = 0; bi < 4; ++bi)
#pragma unroll
    for (int ji = 0; ji < 4; ++ji)
      part[(size_t)kb * 4096 + (bg + 8 * bi) * 128 + (jg + 32 * ji)] = acc[bi][ji];
}

// --------------- reduce split-K partials, add bias, leaky_relu ---------------
__global__ __launch_bounds__(256) void k_fc1_reduce(const float* __restrict__ part,
                                                    const float* __restrict__ fb,
                                                    float* __restrict__ z) {
  int t = blockIdx.x * 256 + threadIdx.x;  // 4096 = 32b x 128j
  if (t >= 4096) return;
  float s = 0.f;
  for (int i = 0; i < 784; ++i) s += part[(size_t)i * 4096 + t];
  s += fb[t % 128];
  z[t] = (s > 0.f) ? s : 0.01f * s;
}

// ---------- head: fc2 + log_softmax + diff finalize (single block) -----------
__global__ __launch_bounds__(384) void k_head(const float* __restrict__ z,
                                              const float* __restrict__ w2,
                                              const float* __restrict__ b2,
                                              const float* __restrict__ bsum,
                                              float* __restrict__ out) {
  __shared__ float lg[32][11];
  __shared__ float lse[32];
  __shared__ float sred[384];
  int t = threadIdx.x;

  // diff partial-sum reduction (50176 block sums)
  float s = 0.f;
  for (int i = t; i < 50176; i += 384) s += bsum[i];
  sred[t] = s;
  __syncthreads();
  if (t < 128) sred[t] += sred[t + 128] + sred[t + 256];
  __syncthreads();
  for (int st = 64; st >= 1; st >>= 1) {
    if (t < st) sred[t] += sred[t + st];
    __syncthreads();
  }

  // logits
  if (t < 352) {
    int b = t / 11, j = t % 11;
    float acc = b2[j];
    for (int d = 0; d < 128; ++d) acc += z[b * 128 + d] * w2[j * 128 + d];
    lg[b][j] = acc;
  }
  __syncthreads();
  if (t < 32) {
    float mx = -3.4e38f;
    for (int j = 0; j < 11; ++j) mx = fmaxf(mx, lg[t][j]);
    float se = 0.f;
    for (int j = 0; j < 11; ++j) se += expf(lg[t][j] - mx);
    lse[t] = mx + logf(se);
  }
  __syncthreads();
  if (t < 352) { int b = t / 11, j = t % 11; out[t] = lg[b][j] - lse[b]; }
  if (t == 352) out[352] = 1.25f * sred[0] / 12845056.0f;
}

// ---------------------------------------------------------------------------
extern "C" void kernel_launch(void* const* d_in, const int* in_sizes, int n_in,
                              void* d_out, int out_size, void* d_ws, size_t ws_size,
                              hipStream_t stream) {
  const float* x    = (const float*)d_in[0];
  const float* c1w  = (const float*)d_in[1];
  const float* c1b  = (const float*)d_in[2];
  const float* c2w  = (const float*)d_in[3];
  const float* c2b  = (const float*)d_in[4];
  const float* c3w  = (const float*)d_in[5];
  const float* c3b  = (const float*)d_in[6];
  const float* c4w  = (const float*)d_in[7];
  const float* c4b  = (const float*)d_in[8];
  const float* bn1g = (const float*)d_in[9];
  const float* bn1b = (const float*)d_in[10];
  const float* bn1m = (const float*)d_in[11];
  const float* bn1v = (const float*)d_in[12];
  const float* bn2g = (const float*)d_in[13];
  const float* bn2b = (const float*)d_in[14];
  const float* bn2m = (const float*)d_in[15];
  const float* bn2v = (const float*)d_in[16];
  const float* bn3g = (const float*)d_in[17];
  const float* bn3b = (const float*)d_in[18];
  const float* bn3m = (const float*)d_in[19];
  const float* bn3v = (const float*)d_in[20];
  const float* bn4g = (const float*)d_in[21];
  const float* bn4b = (const float*)d_in[22];
  const float* bn4m = (const float*)d_in[23];
  const float* bn4v = (const float*)d_in[24];
  const float* qw   = (const float*)d_in[25];
  const float* qcb  = (const float*)d_in[26];
  const float* emb  = (const float*)d_in[27];
  const float* f1w  = (const float*)d_in[28];
  const float* f1b  = (const float*)d_in[29];
  const float* f2w  = (const float*)d_in[30];
  const float* f2b  = (const float*)d_in[31];

  float* ws  = (float*)d_ws;
  float* out = (float*)d_out;

  float* p1   = ws + OFF_P1;
  float* p2   = ws + OFF_P2;
  float* h3   = ws + OFF_H3;
  float* h4   = ws + OFF_H4;
  float* hq   = ws + OFF_HQ;
  float* qn   = ws + OFF_QN;
  int*   ind  = (int*)(ws + OFF_IND);
  float* en   = ws + OFF_EN;
  float* part = ws + OFF_PART;
  float* z    = ws + OFF_Z;
  float* bsum = ws + OFF_BSUM;

  k_enorm<<<4, 256, 0, stream>>>(emb, en);
  k_conv1_pool<<<25088, 256, 0, stream>>>(x, c1w, c1b, bn1g, bn1b, bn1m, bn1v, p1);
  k_conv2_pool<<<3136, 256, 0, stream>>>(p1, c2w, c2b, bn2g, bn2b, bn2m, bn2v, p2);
  // conv3: CO=64 -> 2 co-groups; grid = 32 b * 7 ytiles * 2 = 448
  k_conv3x3_lds<32, 64><<<448, 256, 0, stream>>>(p2, c3w, c3b, bn3g, bn3b, bn3m, bn3v, h3);
  // conv4: CO=128 -> 4 co-groups; grid = 32 * 7 * 4 = 896
  k_conv3x3_lds<64, 128><<<896, 256, 0, stream>>>(h3, c4w, c4b, bn4g, bn4b, bn4m, bn4v, h4);
  k_qconv<<<1568, 256, 0, stream>>>(h4, qw, qcb, hq);
  k_vq_argmin<<<1568, 256, 0, stream>>>(hq, emb, en, ind);
  k_gather_diff<<<50176, 256, 0, stream>>>(hq, emb, ind, qn, bsum);
  k_fc1<<<784, 256, 0, stream>>>(qn, f1w, part);
  k_fc1_reduce<<<16, 256, 0, stream>>>(part, f1b, z);
  k_head<<<1, 384, 0, stream>>>(z, f2w, f2b, bsum, out);
}